// Round 1
// baseline (2092.108 us; speedup 1.0000x reference)
//
#include <hip/hip_runtime.h>

#define BINS 1024
#define DIM  128
#define NTHREADS 256

// Kernel 1: per-row nearest codebook entry (fp32, mirrors reference expression).
// Each thread owns one row; embed[b][k] addresses are wave-uniform -> scalar loads.
__global__ __launch_bounds__(NTHREADS) void vq_dist_argmax(
    const float* __restrict__ x,
    const float* __restrict__ embed,
    float* __restrict__ ind_f)           // [N] indices as float (d_out tail)
{
    __shared__ float esq_s[BINS];
    // Per-block e_sq (1024 sums of 128 squares) — cheap, keeps everything fused.
    for (int b = threadIdx.x; b < BINS; b += NTHREADS) {
        const float* e = embed + b * DIM;
        float s = 0.f;
        #pragma unroll
        for (int k = 0; k < DIM; ++k) s = fmaf(e[k], e[k], s);
        esq_s[b] = s;
    }
    __syncthreads();

    const int row = blockIdx.x * NTHREADS + threadIdx.x;

    // Load this thread's row into registers (32 x float4).
    float xr[DIM];
    {
        const float4* xv = reinterpret_cast<const float4*>(x + (size_t)row * DIM);
        #pragma unroll
        for (int k = 0; k < DIM / 4; ++k) {
            float4 v = xv[k];
            xr[4*k+0] = v.x; xr[4*k+1] = v.y; xr[4*k+2] = v.z; xr[4*k+3] = v.w;
        }
    }

    float xsq = 0.f;
    #pragma unroll
    for (int k = 0; k < DIM; ++k) xsq = fmaf(xr[k], xr[k], xsq);

    float best  = -3.402823466e38f;
    int   bestb = 0;
    for (int b = 0; b < BINS; ++b) {
        const float* __restrict__ e = embed + b * DIM;  // uniform address
        float a0 = 0.f, a1 = 0.f, a2 = 0.f, a3 = 0.f;   // 4-way ILP chains
        #pragma unroll
        for (int k = 0; k < DIM; k += 4) {
            a0 = fmaf(xr[k+0], e[k+0], a0);
            a1 = fmaf(xr[k+1], e[k+1], a1);
            a2 = fmaf(xr[k+2], e[k+2], a2);
            a3 = fmaf(xr[k+3], e[k+3], a3);
        }
        float dot = (a0 + a1) + (a2 + a3);
        // Mirror reference: dist = -((x_sq - 2*dot) + e_sq); 2*dot exact, fma = one rounding.
        float d = -(fmaf(-2.f, dot, xsq) + esq_s[b]);
        if (d > best) { best = d; bestb = b; }   // strict > == first-wins (jnp.argmax)
    }
    ind_f[row] = (float)bestb;
}

// Kernel 2: quantize = embed[ind], fully coalesced float4 writes.
__global__ __launch_bounds__(256) void vq_gather(
    const float* __restrict__ embed,
    const float* __restrict__ ind_f,
    float4* __restrict__ out)            // N*DIM/4 float4
{
    int i   = blockIdx.x * 256 + threadIdx.x;   // over N*DIM/4
    int row = i >> 5;                           // DIM/4 == 32
    int k   = i & 31;
    int b   = (int)ind_f[row];
    out[i] = reinterpret_cast<const float4*>(embed)[b * (DIM / 4) + k];
}

extern "C" void kernel_launch(void* const* d_in, const int* in_sizes, int n_in,
                              void* d_out, int out_size, void* d_ws, size_t ws_size,
                              hipStream_t stream) {
    const float* x     = (const float*)d_in[0];   // [B*T, 128] fp32
    const float* embed = (const float*)d_in[1];   // [1024, 128] fp32
    float* out = (float*)d_out;

    const int N = in_sizes[0] / DIM;              // 262144
    float* ind_f = out + (size_t)N * DIM;         // output 1 region (indices as float)

    vq_dist_argmax<<<N / NTHREADS, NTHREADS, 0, stream>>>(x, embed, ind_f);

    const int total4 = N * (DIM / 4);             // 8388608 float4 elements
    vq_gather<<<total4 / 256, 256, 0, stream>>>(embed, ind_f, (float4*)out);
}